// Round 6
// baseline (191.074 us; speedup 1.0000x reference)
//
#include <hip/hip_runtime.h>

#define NJ   17
#define FD   128
#define NC   128
#define NNZ  49
#define FPT  16                 // frames per tile
#define XROW (NJ*FD)            // 2176 floats per frame
#define WS_WT 65536             // ws offset of wt[128][64] bf16

typedef __attribute__((ext_vector_type(8))) short bf16x8;
typedef __attribute__((ext_vector_type(4))) float f32x4;

__device__ __forceinline__ ushort f2bf(float f) {   // f32 -> bf16 RNE
  unsigned u = __float_as_uint(f);
  u = (u + 0x7fffu + ((u >> 16) & 1u)) >> 16;
  return (ushort)u;
}
__device__ __forceinline__ float bf2f(ushort s) {
  return __uint_as_float(((unsigned)s) << 16);
}
__device__ __forceinline__ unsigned cvtpk(float a, float b) {
  unsigned r;
  asm("v_cvt_pk_bf16_f32 %0, %1, %2" : "=v"(r) : "v"(a), "v"(b));
  return r;
}
__device__ __forceinline__ bf16x8 pack8(float4 a, float4 b) {
  union { unsigned u[4]; bf16x8 v; } r;
  r.u[0] = cvtpk(a.x, a.y); r.u[1] = cvtpk(a.z, a.w);
  r.u[2] = cvtpk(b.x, b.y); r.u[3] = cvtpk(b.z, b.w);
  return r.v;
}
__device__ __forceinline__ void axpy(f32x4& o, float s, f32x4 h) {
  o[0] += s * h[0]; o[1] += s * h[1]; o[2] += s * h[2]; o[3] += s * h[3];
}

// ---------------------------------------------------------------------------
// Human3.6M skeleton is a compile-time constant (parents fixed in reference).
// Per column: diag nnz-index (or -1), and off-diag (local j, nnz-index) list,
// nnz index k in np.nonzero row-major order. Verified: totals 23 (H0) + 26
// (H1) = 49 entries, rp = {0,4,7,10,12,15,18,20,23,28,31,33,36,39,41,44,47,49}.
// ---------------------------------------------------------------------------
struct CI { int col, dk, n, jl[3], kk[3]; };
constexpr CI TAB0[9] = {          // j-half 0: joints 0..7, cols 0..8
  {0,  0, 3, {1,4,7}, {4,12,20}},
  {1,  5, 2, {0,2,0}, {1,7,0}},
  {2,  8, 2, {1,3,0}, {6,10,0}},
  {3, 11, 1, {2,0,0}, {9,0,0}},
  {4, 13, 2, {0,5,0}, {2,15,0}},
  {5, 16, 2, {4,6,0}, {14,18,0}},
  {6, 19, 1, {5,0,0}, {17,0,0}},
  {7, 21, 1, {0,0,0}, {3,0,0}},
  {8, -1, 1, {7,0,0}, {22,0,0}},
};
constexpr CI TAB1[10] = {         // j-half 1: joints 8..16 (local j-8), cols 7..16
  {7, -1, 1, {0,0,0}, {23,0,0}},
  {8, 24, 3, {1,3,6}, {28,33,41}},
  {9, 29, 2, {0,2,0}, {25,31,0}},
  {10,32, 1, {1,0,0}, {30,0,0}},
  {11,34, 2, {0,4,0}, {26,36,0}},
  {12,37, 2, {3,5,0}, {35,39,0}},
  {13,40, 1, {4,0,0}, {38,0,0}},
  {14,42, 2, {0,7,0}, {27,44,0}},
  {15,45, 2, {6,8,0}, {43,47,0}},
  {16,48, 1, {7,0,0}, {46,0,0}},
};
constexpr int RP[NJ + 1] = {0,4,7,10,12,15,18,20,23,28,31,33,36,39,41,44,47,49};

// ---------------------------------------------------------------------------
// Prep (17 blocks x 256):
//  blocks 0..15: pack W f32 [2][128][128] -> bf16 MFMA-B-frag layout:
//                Wpack bf16 idx = n*128 + kb*8 + q <=> W[n>>7][kb*8+q][n&127]
//  block 16:     adjacency softmax -> wt[c][64] bf16 (k-major per channel)
// ---------------------------------------------------------------------------
__global__ void prep_pack_kernel(const float* __restrict__ W,
                                 const float* __restrict__ e,
                                 bf16x8* __restrict__ Wpack,
                                 ushort* __restrict__ wt) {
  const int tid = threadIdx.x;
  if (blockIdx.x < 16) {
    const int idx = blockIdx.x * 256 + tid, n = idx >> 4, kb = idx & 15;
    const float* Wp = W + (size_t)(n >> 7) * (FD * NC) + (n & 127);
    bf16x8 v;
#pragma unroll
    for (int q = 0; q < 8; ++q) v[q] = (short)f2bf(Wp[(size_t)(kb * 8 + q) * NC]);
    Wpack[idx] = v;
  } else if (tid < NC) {
    const int c = tid;
    for (int j = 0; j < NJ; ++j) {
      const int k0 = RP[j], k1 = RP[j + 1];
      float m = -1e30f;
      for (int k = k0; k < k1; ++k) m = fmaxf(m, e[c * NNZ + k]);
      float s = 0.f;
      for (int k = k0; k < k1; ++k) s += expf(e[c * NNZ + k] - m);
      const float inv = 1.f / s;
      for (int k = k0; k < k1; ++k) wt[c * 64 + k] = f2bf(expf(e[c * NNZ + k] - m) * inv);
    }
    for (int k = NNZ; k < 64; ++k) wt[c * 64 + k] = 0;
  }
}

// ---------------------------------------------------------------------------
// Per-tile work for one wave: M = 16 frames, this wave's (j-half, 32 channels).
// For each col: A-frags direct from global (f32 -> cvt_pk bf16), MFMA h0/h1,
// then scale-accumulate into per-joint accumulators (wnorm is lane-uniform
// per D-row since D: col=lane&15=channel, row=(lane>>4)*4+q=frame).
// ---------------------------------------------------------------------------
template <int HALF, int JN, int NCOLS>
__device__ __forceinline__ void tile_work(const float* __restrict__ xt,
                                          float* __restrict__ ob,
                                          const bf16x8 (&bfr)[2][2][4],
                                          const bf16x8 (&wtp)[2][7],
                                          int l15, int l4, int cb) {
  const CI* TT = HALF ? TAB1 : TAB0;
  f32x4 oa[JN][2];
#pragma unroll
  for (int j = 0; j < JN; ++j) {
    oa[j][0] = (f32x4){0.f, 0.f, 0.f, 0.f};
    oa[j][1] = (f32x4){0.f, 0.f, 0.f, 0.f};
  }
#pragma unroll
  for (int ci = 0; ci < NCOLS; ++ci) {
    const int col = TT[ci].col, dk = TT[ci].dk, nn = TT[ci].n;
    const float* ap = xt + l15 * XROW + col * FD + l4 * 8;
    const float4 a00 = *(const float4*)(ap +  0), a01 = *(const float4*)(ap +   4);
    const float4 a10 = *(const float4*)(ap + 32), a11 = *(const float4*)(ap +  36);
    const float4 a20 = *(const float4*)(ap + 64), a21 = *(const float4*)(ap +  68);
    const float4 a30 = *(const float4*)(ap + 96), a31 = *(const float4*)(ap + 100);
    bf16x8 af[4];
    af[0] = pack8(a00, a01); af[1] = pack8(a10, a11);
    af[2] = pack8(a20, a21); af[3] = pack8(a30, a31);

    f32x4 h1[2] = {(f32x4){0.f,0.f,0.f,0.f}, (f32x4){0.f,0.f,0.f,0.f}};
#pragma unroll
    for (int ks = 0; ks < 4; ++ks) {
      h1[0] = __builtin_amdgcn_mfma_f32_16x16x32_bf16(af[ks], bfr[1][0][ks], h1[0], 0, 0, 0);
      h1[1] = __builtin_amdgcn_mfma_f32_16x16x32_bf16(af[ks], bfr[1][1][ks], h1[1], 0, 0, 0);
    }
    if (dk >= 0) {                       // diagonal term (uses W0 product)
      f32x4 h0[2] = {(f32x4){0.f,0.f,0.f,0.f}, (f32x4){0.f,0.f,0.f,0.f}};
#pragma unroll
      for (int ks = 0; ks < 4; ++ks) {
        h0[0] = __builtin_amdgcn_mfma_f32_16x16x32_bf16(af[ks], bfr[0][0][ks], h0[0], 0, 0, 0);
        h0[1] = __builtin_amdgcn_mfma_f32_16x16x32_bf16(af[ks], bfr[0][1][ks], h0[1], 0, 0, 0);
      }
      const int jd = col - (HALF ? 8 : 0);
#pragma unroll
      for (int nt = 0; nt < 2; ++nt)
        axpy(oa[jd][nt], bf2f((ushort)wtp[nt][dk >> 3][dk & 7]), h0[nt]);
    }
#pragma unroll
    for (int o = 0; o < nn; ++o) {       // off-diagonal terms (W1 product)
      const int jl = TT[ci].jl[o], k = TT[ci].kk[o];
#pragma unroll
      for (int nt = 0; nt < 2; ++nt)
        axpy(oa[jl][nt], bf2f((ushort)wtp[nt][k >> 3][k & 7]), h1[nt]);
    }
  }
  const int jb = HALF ? 8 : 0;
#pragma unroll
  for (int j = 0; j < JN; ++j)
#pragma unroll
    for (int nt = 0; nt < 2; ++nt)
#pragma unroll
      for (int q = 0; q < 4; ++q)
        ob[(size_t)(l4 * 4 + q) * XROW + (jb + j) * FD + cb + nt * 16 + l15] =
            oa[j][nt][q];
}

// ---------------------------------------------------------------------------
// Fused kernel: no LDS, no barriers. 4 independent waves per block:
// half = w&1 (joints 0-7 / 8-16), channel group = (blk-member)*64 + (w>>1)*32.
// blockIdx mapping keeps the two 64-channel members of a tile on the SAME XCD
// (pair = blocks b, b+8). Each slot handles 4 consecutive tiles (557 KB x).
// ---------------------------------------------------------------------------
__global__ __launch_bounds__(256, 2) void fused_kernel(
    const float*  __restrict__ x,
    const bf16x8* __restrict__ Wpack,
    const ushort* __restrict__ wt,
    float*        __restrict__ out,
    int ntiles) {
  const int tid = threadIdx.x;
  const int w = tid >> 6, lane = tid & 63, l15 = lane & 15, l4 = lane >> 4;
  const int g = blockIdx.x >> 4, r = blockIdx.x & 15;
  const int slot = g * 8 + (r & 7);
  const int cb = (r >> 3) * 64 + (w >> 1) * 32;
  const int half = w & 1;

  // persistent B fragments: [sel][nt][ks], 64 VGPR
  bf16x8 bfr[2][2][4];
#pragma unroll
  for (int sel = 0; sel < 2; ++sel)
#pragma unroll
    for (int nt = 0; nt < 2; ++nt) {
      const int c = cb + nt * 16 + l15;
#pragma unroll
      for (int ks = 0; ks < 4; ++ks)
        bfr[sel][nt][ks] = Wpack[(sel * 128 + c) * 16 + ks * 4 + l4];
    }
  // persistent packed softmax weights: lane's channel rows, 14 VGPR
  bf16x8 wtp[2][7];
#pragma unroll
  for (int nt = 0; nt < 2; ++nt) {
    const int c = cb + nt * 16 + l15;
#pragma unroll
    for (int rr = 0; rr < 7; ++rr)
      wtp[nt][rr] = *(const bf16x8*)(wt + c * 64 + rr * 8);
  }

#pragma unroll 1
  for (int i = 0; i < 4; ++i) {
    const int t = slot * 4 + i;
    if (t >= ntiles) break;
    const float* xt = x + (size_t)t * (FPT * XROW);
    float* ob = out + (size_t)t * (FPT * XROW);
    if (half == 0) tile_work<0, 8, 9>(xt, ob, bfr, wtp, l15, l4, cb);
    else           tile_work<1, 9, 10>(xt, ob, bfr, wtp, l15, l4, cb);
  }
}

// ---------------------------------------------------------------------------
extern "C" void kernel_launch(void* const* d_in, const int* in_sizes, int n_in,
                              void* d_out, int out_size, void* d_ws, size_t ws_size,
                              hipStream_t stream) {
  const float* x = (const float*)d_in[0];   // [B,T,J,F]
  const float* W = (const float*)d_in[1];   // [2,F,C]
  const float* e = (const float*)d_in[2];   // [C,NNZ]
  float* out = (float*)d_out;

  bf16x8* Wpack = (bf16x8*)d_ws;
  ushort* wt    = (ushort*)((char*)d_ws + WS_WT);

  prep_pack_kernel<<<17, 256, 0, stream>>>(W, e, Wpack, wt);

  const int frames = in_sizes[0] / XROW;    // 15552
  const int ntiles = frames / FPT;          // 972
  const int slots  = (ntiles + 3) / 4;      // 243
  const int groups = (slots + 7) / 8;       // 31
  fused_kernel<<<groups * 16, 256, 0, stream>>>(x, Wpack, wt, out, ntiles);
}

// Round 7
// 99.812 us; speedup vs baseline: 1.9143x; 1.9143x over previous
//
#include <hip/hip_runtime.h>

#define NJ   17
#define FD   128
#define NC   128
#define NNZ  49
#define FPT  16                 // frames per tile (= MFMA M)
#define XROW (NJ*FD)            // 2176 floats per frame
#define WS_WT 65536             // ws offset of wt[128][64] bf16

typedef __attribute__((ext_vector_type(8))) short bf16x8;
typedef __attribute__((ext_vector_type(4))) float f32x4;

__device__ __forceinline__ ushort f2bf(float f) {   // f32 -> bf16 RNE
  unsigned u = __float_as_uint(f);
  u = (u + 0x7fffu + ((u >> 16) & 1u)) >> 16;
  return (ushort)u;
}
__device__ __forceinline__ float bf2f(ushort s) {
  return __uint_as_float(((unsigned)s) << 16);
}
__device__ __forceinline__ unsigned cvtpk(float a, float b) {
  unsigned r;
  asm("v_cvt_pk_bf16_f32 %0, %1, %2" : "=v"(r) : "v"(a), "v"(b));
  return r;
}
__device__ __forceinline__ bf16x8 pack8(float4 a, float4 b) {
  union { unsigned u[4]; bf16x8 v; } r;
  r.u[0] = cvtpk(a.x, a.y); r.u[1] = cvtpk(a.z, a.w);
  r.u[2] = cvtpk(b.x, b.y); r.u[3] = cvtpk(b.z, b.w);
  return r.v;
}
__device__ __forceinline__ void axpy(f32x4& o, float s, f32x4 h) {
  o[0] += s * h[0]; o[1] += s * h[1]; o[2] += s * h[2]; o[3] += s * h[3];
}

// ---------------------------------------------------------------------------
// Compile-time Human3.6M skeleton tables (validated end-to-end in round 6).
// Per column: diag nnz-index dk (or -1), off-diag (local out joint, nnz-k).
// ---------------------------------------------------------------------------
struct CI { int col, dk, n, jl[3], kk[3]; };
constexpr CI TAB0[9] = {          // half 0: out joints 0..7, cols 0..8
  {0,  0, 3, {1,4,7}, {4,12,20}},
  {1,  5, 2, {0,2,0}, {1,7,0}},
  {2,  8, 2, {1,3,0}, {6,10,0}},
  {3, 11, 1, {2,0,0}, {9,0,0}},
  {4, 13, 2, {0,5,0}, {2,15,0}},
  {5, 16, 2, {4,6,0}, {14,18,0}},
  {6, 19, 1, {5,0,0}, {17,0,0}},
  {7, 21, 1, {0,0,0}, {3,0,0}},
  {8, -1, 1, {7,0,0}, {22,0,0}},
};
constexpr CI TAB1[10] = {         // half 1: out joints 8..16 (local j-8), cols 7..16
  {7, -1, 1, {0,0,0}, {23,0,0}},
  {8, 24, 3, {1,3,6}, {28,33,41}},
  {9, 29, 2, {0,2,0}, {25,31,0}},
  {10,32, 1, {1,0,0}, {30,0,0}},
  {11,34, 2, {0,4,0}, {26,36,0}},
  {12,37, 2, {3,5,0}, {35,39,0}},
  {13,40, 1, {4,0,0}, {38,0,0}},
  {14,42, 2, {0,7,0}, {27,44,0}},
  {15,45, 2, {6,8,0}, {43,47,0}},
  {16,48, 1, {7,0,0}, {46,0,0}},
};
constexpr int RP[NJ + 1] = {0,4,7,10,12,15,18,20,23,28,31,33,36,39,41,44,47,49};

// ---------------------------------------------------------------------------
// Prep (17 blocks x 256) — unchanged from round 6 (validated):
//  blocks 0..15: pack W f32 [2][128][128] -> bf16 MFMA-B-frag layout
//                Wpack bf16 idx = n*128 + kb*8 + q <=> W[n>>7][kb*8+q][n&127]
//  block 16:     adjacency softmax -> wt[c][64] bf16 (k-major per channel)
// ---------------------------------------------------------------------------
__global__ void prep_pack_kernel(const float* __restrict__ W,
                                 const float* __restrict__ e,
                                 bf16x8* __restrict__ Wpack,
                                 ushort* __restrict__ wt) {
  const int tid = threadIdx.x;
  if (blockIdx.x < 16) {
    const int idx = blockIdx.x * 256 + tid, n = idx >> 4, kb = idx & 15;
    const float* Wp = W + (size_t)(n >> 7) * (FD * NC) + (n & 127);
    bf16x8 v;
#pragma unroll
    for (int q = 0; q < 8; ++q) v[q] = (short)f2bf(Wp[(size_t)(kb * 8 + q) * NC]);
    Wpack[idx] = v;
  } else if (tid < NC) {
    const int c = tid;
    for (int j = 0; j < NJ; ++j) {
      const int k0 = RP[j], k1 = RP[j + 1];
      float m = -1e30f;
      for (int k = k0; k < k1; ++k) m = fmaxf(m, e[c * NNZ + k]);
      float s = 0.f;
      for (int k = k0; k < k1; ++k) s += expf(e[c * NNZ + k] - m);
      const float inv = 1.f / s;
      for (int k = k0; k < k1; ++k) wt[c * 64 + k] = f2bf(expf(e[c * NNZ + k] - m) * inv);
    }
    for (int k = NNZ; k < 64; ++k) wt[c * 64 + k] = 0;
  }
}

// ---------------------------------------------------------------------------
// Per-half body. Block = 8 waves; wave w owns channels [w*16, w*16+16).
// Stage the half's CONTIGUOUS col-slice x[tile, :, COL0*128 .. (COL0+NCOL)*128)
// into LDS bf16 (coalesced float4 reads, XOR-swizzled (frame&7)<<4 writes),
// then per col: A-frags via ds_read_b128, MFMA h1 (+h0 if diag), in-register
// scale-accumulate with lane-uniform softmax weights, direct stores.
// ---------------------------------------------------------------------------
template <int HALF>
__device__ __forceinline__ void half_work(const float* __restrict__ xt,
                                          float* __restrict__ ob,
                                          const bf16x8* __restrict__ Wpack,
                                          const ushort* __restrict__ wt,
                                          short* xs, int tid) {
  constexpr int COL0 = HALF ? 7 : 0;
  constexpr int NCOL = HALF ? 10 : 9;
  constexpr int JN   = HALF ? 9 : 8;
  constexpr int JB   = HALF ? 8 : 0;
  constexpr int NCI  = HALF ? 10 : 9;
  constexpr int NGRP = FPT * NCOL * 16;   // 8-float groups in the slice
  const CI* TT = HALF ? TAB1 : TAB0;

  const int w = tid >> 6, lane = tid & 63, l15 = lane & 15, l4 = lane >> 4;
  const int cb = w * 16;
  const int c  = cb + l15;

  // ---- staging loads (coalesced: consecutive tid -> consecutive 32B) ----
  float4 v[10];
#pragma unroll
  for (int i = 0; i < 5; ++i) {
    const int g = tid + i * 512;
    if (NGRP % 512 == 0 || g < NGRP) {
      const int fr = g / (NCOL * 16), rem = g - fr * (NCOL * 16);
      const float* sp = xt + (size_t)fr * XROW + COL0 * FD + rem * 8;
      v[2 * i]     = *(const float4*)(sp);
      v[2 * i + 1] = *(const float4*)(sp + 4);
    }
  }

  // ---- persistent B frags (32 VGPR) + softmax weights (7 VGPR) ----
  bf16x8 bfr[2][4];
#pragma unroll
  for (int sel = 0; sel < 2; ++sel)
#pragma unroll
    for (int ks = 0; ks < 4; ++ks)
      bfr[sel][ks] = Wpack[(sel * 128 + c) * 16 + ks * 4 + l4];
  bf16x8 wtp[7];
#pragma unroll
  for (int r = 0; r < 7; ++r)
    wtp[r] = *(const bf16x8*)(wt + c * 64 + r * 8);

  // ---- staging writes (bf16, swizzled) ----
#pragma unroll
  for (int i = 0; i < 5; ++i) {
    const int g = tid + i * 512;
    if (NGRP % 512 == 0 || g < NGRP) {
      const int fr = g / (NCOL * 16);
      const int byte = (g * 16) ^ ((fr & 7) << 4);
      *(bf16x8*)((char*)xs + byte) = pack8(v[2 * i], v[2 * i + 1]);
    }
  }
  __syncthreads();

  // ---- accumulators: this wave's 16 channels, all JN out joints ----
  f32x4 oa[JN];
#pragma unroll
  for (int j = 0; j < JN; ++j) oa[j] = (f32x4){0.f, 0.f, 0.f, 0.f};

#pragma unroll
  for (int ci = 0; ci < NCI; ++ci) {
    const int lc = TT[ci].col - COL0, dk = TT[ci].dk, nn = TT[ci].n;
    // A-frag: frame = l15, k = ks*32 + l4*8 + e
    bf16x8 af[4];
#pragma unroll
    for (int ks = 0; ks < 4; ++ks) {
      const int byte = l15 * (NCOL * 256) + lc * 256 +
                       (((ks * 4 + l4) * 16) ^ ((l15 & 7) << 4));
      af[ks] = *(const bf16x8*)((const char*)xs + byte);
    }
    f32x4 h1 = (f32x4){0.f, 0.f, 0.f, 0.f};
#pragma unroll
    for (int ks = 0; ks < 4; ++ks)
      h1 = __builtin_amdgcn_mfma_f32_16x16x32_bf16(af[ks], bfr[1][ks], h1, 0, 0, 0);
    if (dk >= 0) {                       // diagonal term (W0 product)
      f32x4 h0 = (f32x4){0.f, 0.f, 0.f, 0.f};
#pragma unroll
      for (int ks = 0; ks < 4; ++ks)
        h0 = __builtin_amdgcn_mfma_f32_16x16x32_bf16(af[ks], bfr[0][ks], h0, 0, 0, 0);
      axpy(oa[TT[ci].col - JB], bf2f((ushort)wtp[dk >> 3][dk & 7]), h0);
    }
#pragma unroll
    for (int o = 0; o < 3; ++o)
      if (o < nn)
        axpy(oa[TT[ci].jl[o]], bf2f((ushort)wtp[TT[ci].kk[o] >> 3][TT[ci].kk[o] & 7]), h1);
  }

  // ---- stores: D row = l4*4+q = frame, col = l15 = channel ----
#pragma unroll
  for (int j = 0; j < JN; ++j)
#pragma unroll
    for (int q = 0; q < 4; ++q)
      ob[(size_t)(l4 * 4 + q) * XROW + (JB + j) * FD + c] = oa[j][q];
}

// ---------------------------------------------------------------------------
__global__ __launch_bounds__(512, 4) void fused_kernel(
    const float*  __restrict__ x,
    const bf16x8* __restrict__ Wpack,
    const ushort* __restrict__ wt,
    float*        __restrict__ out) {
  __shared__ __align__(16) short xs[FPT * 10 * FD];   // 40 KB (max of halves)
  const int tile = blockIdx.x >> 1;
  const float* xt = x + (size_t)tile * (FPT * XROW);
  float* ob = out + (size_t)tile * (FPT * XROW);
  if (blockIdx.x & 1) half_work<1>(xt, ob, Wpack, wt, xs, threadIdx.x);
  else                half_work<0>(xt, ob, Wpack, wt, xs, threadIdx.x);
}

// ---------------------------------------------------------------------------
extern "C" void kernel_launch(void* const* d_in, const int* in_sizes, int n_in,
                              void* d_out, int out_size, void* d_ws, size_t ws_size,
                              hipStream_t stream) {
  const float* x = (const float*)d_in[0];   // [B,T,J,F]
  const float* W = (const float*)d_in[1];   // [2,F,C]
  const float* e = (const float*)d_in[2];   // [C,NNZ]
  float* out = (float*)d_out;

  bf16x8* Wpack = (bf16x8*)d_ws;
  ushort* wt    = (ushort*)((char*)d_ws + WS_WT);

  prep_pack_kernel<<<17, 256, 0, stream>>>(W, e, Wpack, wt);

  const int frames = in_sizes[0] / XROW;    // 15552
  const int ntiles = frames / FPT;          // 972
  fused_kernel<<<ntiles * 2, 512, 0, stream>>>(x, Wpack, wt, out);
}